// Round 22
// baseline (204.228 us; speedup 1.0000x reference)
//
#include <hip/hip_runtime.h>

typedef float  f32x4  __attribute__((ext_vector_type(4)));
typedef float  f32x16 __attribute__((ext_vector_type(16)));
typedef __bf16 bf16x2 __attribute__((ext_vector_type(2)));
typedef __bf16 bf16x4 __attribute__((ext_vector_type(4)));
typedef __bf16 bf16x8 __attribute__((ext_vector_type(8)));
typedef unsigned int u32;
typedef u32 u32x4 __attribute__((ext_vector_type(4)));

#define MFMA16(a, b, c) __builtin_amdgcn_mfma_f32_16x16x32_bf16((a), (b), (c), 0, 0, 0)
#define MFMA32(a, b, c) __builtin_amdgcn_mfma_f32_32x32x16_bf16((a), (b), (c), 0, 0, 0)

constexpr int EMB  = 1024;
constexpr int NSEQ = 2048;
constexpr int NB   = 4;
constexpr int NH   = 16;
constexpr int DH   = 64;
constexpr size_t HSTRIDE = (size_t)NSEQ * DH;        // elements per head (Q/K/V)
constexpr size_t MAT     = (size_t)NB * NSEQ * EMB;  // 8388608
constexpr size_t WSZ     = (size_t)EMB * EMB;        // 1048576
constexpr float  QSCALE  = 0.18033688011112042f;     // 0.125 * log2(e)

__device__ __forceinline__ __bf16 f2bf(float f) { return (__bf16)f; }

__device__ __forceinline__ u32 pkbf(float a, float b) {
  bf16x2 t = {(__bf16)a, (__bf16)b};
  return __builtin_bit_cast(u32, t);
}

// XOR swizzle (involution) for 128B-row tiles (GEMM staging only).
__device__ __forceinline__ int swz(int a) { return a ^ (((a >> 7) & 7) << 4); }

// async global->LDS, 16B per lane; LDS dest = wave-uniform base + lane*16.
__device__ __forceinline__ void gll16(const void* g, void* l) {
  __builtin_amdgcn_global_load_lds((const __attribute__((address_space(1))) unsigned*)g,
                                   (__attribute__((address_space(3))) unsigned*)l, 16, 0, 0);
}

// ================= conversion pre-pass (single launch) =================
__global__ __launch_bounds__(256) void cvt_all(const float* __restrict__ x,
                                               const float* __restrict__ w0,
                                               const float* __restrict__ w1,
                                               const float* __restrict__ w2,
                                               const float* __restrict__ w3,
                                               __bf16* __restrict__ Xbf,
                                               __bf16* __restrict__ Wbf) {
  const int xblocks = (int)(MAT / 4 / 256);
  const int wslice  = (int)(WSZ / 4 / 256);
  const float* src;
  __bf16* dst;
  size_t idx;
  if (blockIdx.x < (unsigned)xblocks) {
    src = x; dst = Xbf;
    idx = (size_t)blockIdx.x * 256 + threadIdx.x;
  } else {
    int j = blockIdx.x - xblocks;
    int z = j / wslice, r = j % wslice;
    const float* srcs[4] = {w0, w1, w2, w3};
    src = srcs[z];
    dst = Wbf + (size_t)z * WSZ;
    idx = (size_t)r * 256 + threadIdx.x;
  }
  f32x4 v = *reinterpret_cast<const f32x4*>(src + idx * 4);
  bf16x4 o = {f2bf(v[0]), f2bf(v[1]), f2bf(v[2]), f2bf(v[3])};
  *reinterpret_cast<bf16x4*>(dst + idx * 4) = o;
}

// ================= fused 3-output QKV GEMM, 128x64 tile =================
// Q -> [b][h][n][d] (prescaled). K,V -> FRAGMENT-MAJOR per (b,h) (r21 proven):
//  K elem (row,d): tile=row>>6, f=((row>>5)&1)*4+(d>>4),
//                  lane=((d>>3)&1)*32+(row&31), i=d&7
//  V elem (kv,d):  tile=kv>>6,  f=((kv>>4)&3)*2+(d>>5),
//                  lane=((kv>>3)&1)*32+(d&31),  i=kv&7
__global__ __launch_bounds__(256) void qkv3(const __bf16* __restrict__ Xbf,
                                            const __bf16* __restrict__ Wbf,
                                            const float* __restrict__ bq,
                                            const float* __restrict__ bk,
                                            const float* __restrict__ bv,
                                            __bf16* __restrict__ Qw,
                                            __bf16* __restrict__ Kw,
                                            __bf16* __restrict__ Vw) {
  __shared__ __align__(16) __bf16 sA[128 * 64];        // 16KB
  __shared__ __align__(16) __bf16 sW[3][64 * 64];      // 3 x 8KB
  const int t = threadIdx.x;
  const int lane = t & 63, w = t >> 6;
  const int l15 = lane & 15, g = lane >> 4;

  // bijective XCD remap over 1024 blocks
  int flat = blockIdx.x + 16 * blockIdx.y;
  int logical = (flat & 7) * 128 + (flat >> 3);
  const int m0 = (logical >> 4) * 128, n0 = (logical & 15) * 64;

  const char* Ac  = (const char*)Xbf;
  const char* Wc[3] = {(const char*)(Wbf + 0 * WSZ),
                       (const char*)(Wbf + 1 * WSZ),
                       (const char*)(Wbf + 2 * WSZ)};

  const int srow = lane >> 3;                          // 8 rows / chunk
  const int scol = ((lane & 7) ^ srow) * 16;           // pre-swizzled source col byte

  int offA[2][2], offB[4][2];
#pragma unroll
  for (int i = 0; i < 2; ++i)
#pragma unroll
    for (int ks = 0; ks < 2; ++ks) {
      int ra = w * 32 + i * 16 + l15;
      offA[i][ks] = (ra * 128 + ((ks * 64 + g * 16) ^ ((l15 & 7) << 4))) >> 1;
    }
#pragma unroll
  for (int i = 0; i < 4; ++i)
#pragma unroll
    for (int ks = 0; ks < 2; ++ks) {
      int rb = i * 16 + l15;
      offB[i][ks] = (rb * 128 + ((ks * 64 + g * 16) ^ ((l15 & 7) << 4))) >> 1;
    }

  f32x4 acc[3][2][4];
#pragma unroll
  for (int m = 0; m < 3; ++m)
#pragma unroll
    for (int i = 0; i < 2; ++i)
#pragma unroll
      for (int j = 0; j < 4; ++j) acc[m][i][j] = f32x4{0.f, 0.f, 0.f, 0.f};

#pragma unroll 1
  for (int k0 = 0; k0 < EMB; k0 += 64) {
#pragma unroll
    for (int p = 0; p < 4; ++p) {
      int c = p * 4 + w;
      gll16(Ac + (size_t)(m0 + c * 8 + srow) * (EMB * 2) + k0 * 2 + scol, sA + c * 512);
    }
#pragma unroll
    for (int p = 0; p < 2; ++p) {
      int c = p * 4 + w;
      size_t rowB = (size_t)(n0 + c * 8 + srow) * (EMB * 2) + k0 * 2 + scol;
#pragma unroll
      for (int mat = 0; mat < 3; ++mat)
        gll16(Wc[mat] + rowB, &sW[mat][c * 512]);
    }
    __syncthreads();   // drains vmcnt: staged tiles visible
#pragma unroll
    for (int ks = 0; ks < 2; ++ks) {
      bf16x8 af[2];
#pragma unroll
      for (int i = 0; i < 2; ++i)
        af[i] = *reinterpret_cast<const bf16x8*>(&sA[offA[i][ks]]);
#pragma unroll
      for (int mat = 0; mat < 3; ++mat) {
        bf16x8 bf[4];
#pragma unroll
        for (int i = 0; i < 4; ++i)
          bf[i] = *reinterpret_cast<const bf16x8*>(&sW[mat][offB[i][ks]]);
#pragma unroll
        for (int mi = 0; mi < 2; ++mi)
#pragma unroll
          for (int ni = 0; ni < 4; ++ni)
            acc[mat][mi][ni] = MFMA16(af[mi], bf[ni], acc[mat][mi][ni]);
      }
    }
    __syncthreads();   // tiles consumed; safe to restage
  }

  // ---- epilogue ----  (C/D: row=(lane>>4)*4+reg, col=lane&15)
  const int hh = n0 >> 6;                              // one head per block
#pragma unroll
  for (int mi = 0; mi < 2; ++mi)
#pragma unroll
    for (int ni = 0; ni < 4; ++ni) {
      int cg = n0 + ni * 16 + l15;
      int d = cg & (DH - 1);
#pragma unroll
      for (int j = 0; j < 4; ++j) {
        int rg = m0 + w * 32 + mi * 16 + g * 4 + j;
        int bb = rg >> 11, r = rg & (NSEQ - 1);
        size_t hb = (size_t)(bb * NH + hh);
        // Q: [b][h][n][d]
        Qw[(hb * NSEQ + r) * DH + d] = f2bf((acc[0][mi][ni][j] + bq[cg]) * QSCALE);
        // K: fragment-major
        size_t kidx = hb * HSTRIDE + (size_t)(r >> 6) * 4096
                    + (size_t)(((((r >> 5) & 1) << 2) + (d >> 4)) * 512)
                    + (size_t)(((((d >> 3) & 1) << 5) + (r & 31)) * 8) + (d & 7);
        Kw[kidx] = f2bf(acc[1][mi][ni][j] + bk[cg]);
      }
      // V: fragment-major; 4 consecutive kv (=i0..i0+3) -> one 8B store
      float bvc = bv[cg];
      int rg0 = m0 + w * 32 + mi * 16 + g * 4;
      int bb = rg0 >> 11, kv0 = rg0 & (NSEQ - 1);
      int kvL = kv0 & 63;
      size_t vaddr = (size_t)(bb * NH + hh) * HSTRIDE + (size_t)(kv0 >> 6) * 4096
                   + (size_t)(((((kvL >> 4) & 3) << 1) + (d >> 5)) * 512)
                   + (size_t)(((((kvL >> 3) & 1) << 5) + (d & 31)) * 8) + (kvL & 7);
      bf16x4 pv = {f2bf(acc[2][mi][ni][0] + bvc), f2bf(acc[2][mi][ni][1] + bvc),
                   f2bf(acc[2][mi][ni][2] + bvc), f2bf(acc[2][mi][ni][3] + bvc)};
      *reinterpret_cast<bf16x4*>(Vw + vaddr) = pv;
    }
}

// ================= output projection (r13 proven: 128x128, 512 blocks = 2/CU) =================
__device__ __forceinline__ void gemm_loop(__bf16* sA, __bf16* sB,
                                          const __bf16* __restrict__ A,
                                          const __bf16* __restrict__ W,
                                          int m0, int n0, f32x4 (&acc)[4][4]) {
  const int t = threadIdx.x;
  const int lane = t & 63, w = t >> 6;
  const int wr = w >> 1, wc = w & 1;
  const int l15 = lane & 15, g = lane >> 4;
  const char* Ac = (const char*)A;
  const char* Wc = (const char*)W;
  const int srow = lane >> 3;
  const int scol = ((lane & 7) ^ srow) * 16;

  int offA[4][2], offB[4][2];
#pragma unroll
  for (int i = 0; i < 4; ++i)
#pragma unroll
    for (int ks = 0; ks < 2; ++ks) {
      int ra = wr * 64 + i * 16 + l15;
      int rb = wc * 64 + i * 16 + l15;
      offA[i][ks] = (ra * 128 + ((ks * 64 + g * 16) ^ ((l15 & 7) << 4))) >> 1;
      offB[i][ks] = (rb * 128 + ((ks * 64 + g * 16) ^ ((l15 & 7) << 4))) >> 1;
    }

#pragma unroll 1
  for (int k0 = 0; k0 < EMB; k0 += 64) {
#pragma unroll
    for (int p = 0; p < 4; ++p) {
      int c = p * 4 + w;
      gll16(Ac + (size_t)(m0 + c * 8 + srow) * (EMB * 2) + k0 * 2 + scol, sA + c * 512);
      gll16(Wc + (size_t)(n0 + c * 8 + srow) * (EMB * 2) + k0 * 2 + scol, sB + c * 512);
    }
    __syncthreads();
    bf16x8 af[4][2], bfr[4][2];
#pragma unroll
    for (int i = 0; i < 4; ++i)
#pragma unroll
      for (int ks = 0; ks < 2; ++ks) {
        af[i][ks]  = *reinterpret_cast<const bf16x8*>(sA + offA[i][ks]);
        bfr[i][ks] = *reinterpret_cast<const bf16x8*>(sB + offB[i][ks]);
      }
#pragma unroll
    for (int ks = 0; ks < 2; ++ks)
#pragma unroll
      for (int mi = 0; mi < 4; ++mi)
#pragma unroll
        for (int ni = 0; ni < 4; ++ni)
          acc[mi][ni] = MFMA16(af[mi][ks], bfr[ni][ks], acc[mi][ni]);
    __syncthreads();
  }
}

__global__ __launch_bounds__(256) void oproj_bf(const __bf16* __restrict__ Abf,
                                                const __bf16* __restrict__ W,
                                                const float* __restrict__ bias,
                                                float* __restrict__ outp) {
  __shared__ __align__(16) __bf16 smem[2][128 * 64];
  int flat = blockIdx.x + 8 * blockIdx.y;
  int logical = (flat & 7) * 64 + (flat >> 3);
  const int m0 = (logical >> 3) * 128, n0 = (logical & 7) * 128;

  f32x4 acc[4][4];
#pragma unroll
  for (int i = 0; i < 4; ++i)
#pragma unroll
    for (int j = 0; j < 4; ++j) acc[i][j] = f32x4{0.f, 0.f, 0.f, 0.f};

  gemm_loop(smem[0], smem[1], Abf, W, m0, n0, acc);

  const int lane = threadIdx.x & 63, w = threadIdx.x >> 6;
  const int wr = w >> 1, wc = w & 1, l15 = lane & 15, g = lane >> 4;
#pragma unroll
  for (int mi = 0; mi < 4; ++mi)
#pragma unroll
    for (int ni = 0; ni < 4; ++ni)
#pragma unroll
      for (int j = 0; j < 4; ++j) {
        int rg = m0 + wr * 64 + mi * 16 + g * 4 + j;
        int cg = n0 + wc * 64 + ni * 16 + l15;
        outp[(size_t)rg * EMB + cg] = acc[mi][ni][j] + bias[cg];
      }
}

// ================= Flash attention: K direct from global, V-only LDS =================
// r21 structure, but K fragments load straight from fragment-major global
// (wave-contiguous 1KB windows, L2-resident) -> LDS reads and staging halve,
// LDS 32KB. V stays LDS-staged (shared across waves). Per-wave math identical.
__global__ __launch_bounds__(512) void flash_kernel(const __bf16* __restrict__ Qb,
                                                    const __bf16* __restrict__ Kb,
                                                    const __bf16* __restrict__ Vb,
                                                    float* __restrict__ attnw,
                                                    __bf16* __restrict__ attnw_bf) {
  __shared__ __align__(16) __bf16 lds[2][8192];   // [buf][ V: 16KB per 128-kv tile ]
  const int t = threadIdx.x;
  const int lane = t & 63, w = t >> 6;            // w in [0,8)
  const int l31 = lane & 31, hi = lane >> 5;

  int flat = blockIdx.x + 8 * (blockIdx.y + NH * blockIdx.z);
  int logical = (flat & 7) * 64 + (flat >> 3);
  const int qt = logical & 7, h = (logical >> 3) & 15, b = logical >> 7;

  const size_t hoff = ((size_t)(b * NH + h)) * HSTRIDE;
  const __bf16* Qh = Qb + hoff;                  // [2048][64]
  const char* Kc = (const char*)(Kb + hoff);     // fragment-major, 8KB per 64-row tile
  const char* Vc = (const char*)(Vb + hoff);     // fragment-major, 8KB per 64-kv tile
  const int q0 = qt * 256 + w * 32;              // this wave's 32 q-rows

  bf16x8 qf[4];
#pragma unroll
  for (int ds = 0; ds < 4; ++ds)
    qf[ds] = *reinterpret_cast<const bf16x8*>(Qh + (size_t)(q0 + l31) * DH + ds * 16 + hi * 8);

  // stage a 128-kv V tile (16KB): pure linear copy, 16 chunks
  auto stage = [&](int bf, int it) {
#pragma unroll
    for (int j = 0; j < 2; ++j) {
      int chunk = w * 2 + j;
      size_t src = (size_t)it * 16384 + chunk * 1024 + lane * 16;
      gll16(Vc + src, &lds[bf][chunk * 512]);
    }
  };

  f32x16 o0{}, o1{};
  float lsum = 0.f;                     // per-lane partial row sum (row q = l31)
  const f32x16 kZero{};                 // hoisted zero C operand
  const int lofs = lane * 8;            // element offset of this lane's fragment slot

  stage(0, 0);
  __syncthreads();

#pragma unroll 1
  for (int it = 0; it < NSEQ / 128; ++it) {
    const int cur = it & 1;
    if (it + 1 < NSEQ / 128) stage(cur ^ 1, it + 1);

#pragma unroll
    for (int sub = 0; sub < 2; ++sub) {
      const __bf16* Vl = lds[cur] + sub * 4096;
      const char* Ksub = Kc + (size_t)it * 16384 + sub * 8192;

      // K fragments straight from global (coalesced 1KB windows, L2-hit)
      bf16x8 kf[2][4];
#pragma unroll
      for (int kt32 = 0; kt32 < 2; ++kt32)
#pragma unroll
        for (int ds = 0; ds < 4; ++ds)
          kf[kt32][ds] = *reinterpret_cast<const bf16x8*>(
              Ksub + (kt32 * 4 + ds) * 1024 + lane * 16);

      f32x16 s0, s1;
      __builtin_amdgcn_s_setprio(1);
      s0 = MFMA32(kf[0][0], qf[0], kZero);
      s1 = MFMA32(kf[1][0], qf[0], kZero);
#pragma unroll
      for (int ds = 1; ds < 4; ++ds) s0 = MFMA32(kf[0][ds], qf[ds], s0);
#pragma unroll
      for (int ds = 1; ds < 4; ++ds) s1 = MFMA32(kf[1][ds], qf[ds], s1);
      __builtin_amdgcn_s_setprio(0);

      bf16x8 vf[4][2];
#pragma unroll
      for (int c = 0; c < 4; ++c)
#pragma unroll
        for (int db = 0; db < 2; ++db)
          vf[c][db] = *reinterpret_cast<const bf16x8*>(Vl + (c * 2 + db) * 512 + lofs);

      // softmax: p = exp2(S) via raw v_exp_f32 (no IEEE denormal fixup)
#pragma unroll
      for (int r = 0; r < 16; ++r) s0[r] = __builtin_amdgcn_exp2f(s0[r]);
#pragma unroll
      for (int r = 0; r < 16; ++r) s1[r] = __builtin_amdgcn_exp2f(s1[r]);

      // denominator on the VALU (slack pipe): tree-sum 32 values
      {
        float t0 = ((s0[0] + s0[1]) + (s0[2] + s0[3])) + ((s0[4] + s0[5]) + (s0[6] + s0[7]));
        float t1 = ((s0[8] + s0[9]) + (s0[10] + s0[11])) + ((s0[12] + s0[13]) + (s0[14] + s0[15]));
        float t2 = ((s1[0] + s1[1]) + (s1[2] + s1[3])) + ((s1[4] + s1[5]) + (s1[6] + s1[7]));
        float t3 = ((s1[8] + s1[9]) + (s1[10] + s1[11])) + ((s1[12] + s1[13]) + (s1[14] + s1[15]));
        lsum += (t0 + t1) + (t2 + t3);
      }

      u32 pk0[8], pk1[8];
#pragma unroll
      for (int j = 0; j < 8; ++j) pk0[j] = pkbf(s0[2 * j], s0[2 * j + 1]);
#pragma unroll
      for (int j = 0; j < 8; ++j) pk1[j] = pkbf(s1[2 * j], s1[2 * j + 1]);

      auto pv_step = [&](u32& a0, u32& a1, u32& a2, u32& a3, int c) {
        asm("v_permlane32_swap_b32 %0, %1" : "+v"(a0), "+v"(a2));
        asm("v_permlane32_swap_b32 %0, %1" : "+v"(a1), "+v"(a3));
        u32x4 wv = {a0, a1, a2, a3};
        bf16x8 pa = __builtin_bit_cast(bf16x8, wv);
        o0 = MFMA32(pa, vf[c][0], o0);
        o1 = MFMA32(pa, vf[c][1], o1);
      };
      __builtin_amdgcn_s_setprio(1);
      pv_step(pk0[0], pk0[1], pk0[2], pk0[3], 0);
      pv_step(pk0[4], pk0[5], pk0[6], pk0[7], 1);
      pv_step(pk1[0], pk1[1], pk1[2], pk1[3], 2);
      pv_step(pk1[4], pk1[5], pk1[6], pk1[7], 3);
      __builtin_amdgcn_s_setprio(0);
    }

    __syncthreads();   // drains staging vmcnt + lgkm; safe buffer flip
  }

  // row total: lane covers half the k's of row q=l31; partner has the rest
  lsum += __shfl_xor(lsum, 32);
  float inv = 1.0f / lsum;

#pragma unroll
  for (int r = 0; r < 16; ++r) {
    int qq = (r & 3) + 8 * (r >> 2) + 4 * hi;
    float invq = __shfl(inv, qq);        // lane qq holds row qq's inv
    int row = q0 + qq;
    float v0 = o0[r] * invq, v1 = o1[r] * invq;
    float* base = attnw + ((size_t)(b * NSEQ + row)) * EMB + h * DH;
    base[l31]      = v0;
    base[32 + l31] = v1;
    __bf16* bb2 = attnw_bf + ((size_t)(b * NSEQ + row)) * EMB + h * DH;
    bb2[l31]      = f2bf(v0);
    bb2[32 + l31] = f2bf(v1);
  }
}

extern "C" void kernel_launch(void* const* d_in, const int* in_sizes, int n_in,
                              void* d_out, int out_size, void* d_ws, size_t ws_size,
                              hipStream_t stream) {
  const float* q  = (const float*)d_in[0];
  const float* Wq = (const float*)d_in[1];
  const float* bq = (const float*)d_in[2];
  const float* Wk = (const float*)d_in[3];
  const float* bk = (const float*)d_in[4];
  const float* Wv = (const float*)d_in[5];
  const float* bv = (const float*)d_in[6];
  const float* Wo = (const float*)d_in[7];
  const float* bo = (const float*)d_in[8];

  float* outp  = (float*)d_out;
  float* attnw = outp + MAT;            // second tuple element

  // ws = Q | K | V | Xbf(->attnw_bf) | Wbf[4]   (bf16; ~75.5 MB, fits: r7)
  __bf16* Qw   = (__bf16*)d_ws;
  __bf16* Kw   = Qw + MAT;              // fragment-major per head
  __bf16* Vw   = Qw + 2 * MAT;          // fragment-major per head
  __bf16* Xbf  = Qw + 3 * MAT;          // aliased as attnw_bf after qkv
  __bf16* Wbf  = Qw + 4 * MAT;

  const int xblocks = (int)(MAT / 4 / 256);
  const int wblocks = (int)(4 * WSZ / 4 / 256);
  cvt_all<<<xblocks + wblocks, 256, 0, stream>>>(q, Wq, Wk, Wv, Wo, Xbf, Wbf);

  qkv3<<<dim3(16, 64), 256, 0, stream>>>(Xbf, Wbf, bq, bk, bv, Qw, Kw, Vw);

  flash_kernel<<<dim3(8, NH, NB), 512, 0, stream>>>(Qw, Kw, Vw, attnw, Xbf);

  oproj_bf<<<dim3(8, 64), 256, 0, stream>>>(Xbf, Wbf + 3 * WSZ, bo, outp);
}

// Round 23
// 185.638 us; speedup vs baseline: 1.1001x; 1.1001x over previous
//
#include <hip/hip_runtime.h>

typedef float  f32x4  __attribute__((ext_vector_type(4)));
typedef float  f32x16 __attribute__((ext_vector_type(16)));
typedef __bf16 bf16x2 __attribute__((ext_vector_type(2)));
typedef __bf16 bf16x4 __attribute__((ext_vector_type(4)));
typedef __bf16 bf16x8 __attribute__((ext_vector_type(8)));
typedef unsigned int u32;
typedef u32 u32x4 __attribute__((ext_vector_type(4)));

#define MFMA16(a, b, c) __builtin_amdgcn_mfma_f32_16x16x32_bf16((a), (b), (c), 0, 0, 0)
#define MFMA32(a, b, c) __builtin_amdgcn_mfma_f32_32x32x16_bf16((a), (b), (c), 0, 0, 0)

constexpr int EMB  = 1024;
constexpr int NSEQ = 2048;
constexpr int NB   = 4;
constexpr int NH   = 16;
constexpr int DH   = 64;
constexpr size_t HSTRIDE = (size_t)NSEQ * DH;        // elements per head (Q/K/V)
constexpr size_t MAT     = (size_t)NB * NSEQ * EMB;  // 8388608
constexpr size_t WSZ     = (size_t)EMB * EMB;        // 1048576
constexpr float  QSCALE  = 0.18033688011112042f;     // 0.125 * log2(e)

__device__ __forceinline__ __bf16 f2bf(float f) { return (__bf16)f; }

__device__ __forceinline__ u32 pkbf(float a, float b) {
  bf16x2 t = {(__bf16)a, (__bf16)b};
  return __builtin_bit_cast(u32, t);
}

// XOR swizzle (involution) for 128B-row tiles (GEMM staging only).
__device__ __forceinline__ int swz(int a) { return a ^ (((a >> 7) & 7) << 4); }

// async global->LDS, 16B per lane; LDS dest = wave-uniform base + lane*16.
__device__ __forceinline__ void gll16(const void* g, void* l) {
  __builtin_amdgcn_global_load_lds((const __attribute__((address_space(1))) unsigned*)g,
                                   (__attribute__((address_space(3))) unsigned*)l, 16, 0, 0);
}

// ================= conversion pre-pass (single launch) =================
__global__ __launch_bounds__(256) void cvt_all(const float* __restrict__ x,
                                               const float* __restrict__ w0,
                                               const float* __restrict__ w1,
                                               const float* __restrict__ w2,
                                               const float* __restrict__ w3,
                                               __bf16* __restrict__ Xbf,
                                               __bf16* __restrict__ Wbf) {
  const int xblocks = (int)(MAT / 4 / 256);
  const int wslice  = (int)(WSZ / 4 / 256);
  const float* src;
  __bf16* dst;
  size_t idx;
  if (blockIdx.x < (unsigned)xblocks) {
    src = x; dst = Xbf;
    idx = (size_t)blockIdx.x * 256 + threadIdx.x;
  } else {
    int j = blockIdx.x - xblocks;
    int z = j / wslice, r = j % wslice;
    const float* srcs[4] = {w0, w1, w2, w3};
    src = srcs[z];
    dst = Wbf + (size_t)z * WSZ;
    idx = (size_t)r * 256 + threadIdx.x;
  }
  f32x4 v = *reinterpret_cast<const f32x4*>(src + idx * 4);
  bf16x4 o = {f2bf(v[0]), f2bf(v[1]), f2bf(v[2]), f2bf(v[3])};
  *reinterpret_cast<bf16x4*>(dst + idx * 4) = o;
}

// ================= fused 3-output QKV GEMM, 128x64 tile =================
// Q -> [b][h][n][d] (prescaled). K,V -> FRAGMENT-MAJOR per (b,h) (r21 proven):
//  K elem (row,d): tile=row>>6, f=((row>>5)&1)*4+(d>>4),
//                  lane=((d>>3)&1)*32+(row&31), i=d&7
//  V elem (kv,d):  tile=kv>>6,  f=((kv>>4)&3)*2+(d>>5),
//                  lane=((kv>>3)&1)*32+(d&31),  i=kv&7
__global__ __launch_bounds__(256) void qkv3(const __bf16* __restrict__ Xbf,
                                            const __bf16* __restrict__ Wbf,
                                            const float* __restrict__ bq,
                                            const float* __restrict__ bk,
                                            const float* __restrict__ bv,
                                            __bf16* __restrict__ Qw,
                                            __bf16* __restrict__ Kw,
                                            __bf16* __restrict__ Vw) {
  __shared__ __align__(16) __bf16 sA[128 * 64];        // 16KB
  __shared__ __align__(16) __bf16 sW[3][64 * 64];      // 3 x 8KB
  const int t = threadIdx.x;
  const int lane = t & 63, w = t >> 6;
  const int l15 = lane & 15, g = lane >> 4;

  // bijective XCD remap over 1024 blocks
  int flat = blockIdx.x + 16 * blockIdx.y;
  int logical = (flat & 7) * 128 + (flat >> 3);
  const int m0 = (logical >> 4) * 128, n0 = (logical & 15) * 64;

  const char* Ac  = (const char*)Xbf;
  const char* Wc[3] = {(const char*)(Wbf + 0 * WSZ),
                       (const char*)(Wbf + 1 * WSZ),
                       (const char*)(Wbf + 2 * WSZ)};

  const int srow = lane >> 3;                          // 8 rows / chunk
  const int scol = ((lane & 7) ^ srow) * 16;           // pre-swizzled source col byte

  int offA[2][2], offB[4][2];
#pragma unroll
  for (int i = 0; i < 2; ++i)
#pragma unroll
    for (int ks = 0; ks < 2; ++ks) {
      int ra = w * 32 + i * 16 + l15;
      offA[i][ks] = (ra * 128 + ((ks * 64 + g * 16) ^ ((l15 & 7) << 4))) >> 1;
    }
#pragma unroll
  for (int i = 0; i < 4; ++i)
#pragma unroll
    for (int ks = 0; ks < 2; ++ks) {
      int rb = i * 16 + l15;
      offB[i][ks] = (rb * 128 + ((ks * 64 + g * 16) ^ ((l15 & 7) << 4))) >> 1;
    }

  f32x4 acc[3][2][4];
#pragma unroll
  for (int m = 0; m < 3; ++m)
#pragma unroll
    for (int i = 0; i < 2; ++i)
#pragma unroll
      for (int j = 0; j < 4; ++j) acc[m][i][j] = f32x4{0.f, 0.f, 0.f, 0.f};

#pragma unroll 1
  for (int k0 = 0; k0 < EMB; k0 += 64) {
#pragma unroll
    for (int p = 0; p < 4; ++p) {
      int c = p * 4 + w;
      gll16(Ac + (size_t)(m0 + c * 8 + srow) * (EMB * 2) + k0 * 2 + scol, sA + c * 512);
    }
#pragma unroll
    for (int p = 0; p < 2; ++p) {
      int c = p * 4 + w;
      size_t rowB = (size_t)(n0 + c * 8 + srow) * (EMB * 2) + k0 * 2 + scol;
#pragma unroll
      for (int mat = 0; mat < 3; ++mat)
        gll16(Wc[mat] + rowB, &sW[mat][c * 512]);
    }
    __syncthreads();   // drains vmcnt: staged tiles visible
#pragma unroll
    for (int ks = 0; ks < 2; ++ks) {
      bf16x8 af[2];
#pragma unroll
      for (int i = 0; i < 2; ++i)
        af[i] = *reinterpret_cast<const bf16x8*>(&sA[offA[i][ks]]);
#pragma unroll
      for (int mat = 0; mat < 3; ++mat) {
        bf16x8 bf[4];
#pragma unroll
        for (int i = 0; i < 4; ++i)
          bf[i] = *reinterpret_cast<const bf16x8*>(&sW[mat][offB[i][ks]]);
#pragma unroll
        for (int mi = 0; mi < 2; ++mi)
#pragma unroll
          for (int ni = 0; ni < 4; ++ni)
            acc[mat][mi][ni] = MFMA16(af[mi], bf[ni], acc[mat][mi][ni]);
      }
    }
    __syncthreads();   // tiles consumed; safe to restage
  }

  // ---- epilogue ----  (C/D: row=(lane>>4)*4+reg, col=lane&15)
  const int hh = n0 >> 6;                              // one head per block
#pragma unroll
  for (int mi = 0; mi < 2; ++mi)
#pragma unroll
    for (int ni = 0; ni < 4; ++ni) {
      int cg = n0 + ni * 16 + l15;
      int d = cg & (DH - 1);
#pragma unroll
      for (int j = 0; j < 4; ++j) {
        int rg = m0 + w * 32 + mi * 16 + g * 4 + j;
        int bb = rg >> 11, r = rg & (NSEQ - 1);
        size_t hb = (size_t)(bb * NH + hh);
        // Q: [b][h][n][d]
        Qw[(hb * NSEQ + r) * DH + d] = f2bf((acc[0][mi][ni][j] + bq[cg]) * QSCALE);
        // K: fragment-major
        size_t kidx = hb * HSTRIDE + (size_t)(r >> 6) * 4096
                    + (size_t)(((((r >> 5) & 1) << 2) + (d >> 4)) * 512)
                    + (size_t)(((((d >> 3) & 1) << 5) + (r & 31)) * 8) + (d & 7);
        Kw[kidx] = f2bf(acc[1][mi][ni][j] + bk[cg]);
      }
      // V: fragment-major; 4 consecutive kv (=i0..i0+3) -> one 8B store
      float bvc = bv[cg];
      int rg0 = m0 + w * 32 + mi * 16 + g * 4;
      int bb = rg0 >> 11, kv0 = rg0 & (NSEQ - 1);
      int kvL = kv0 & 63;
      size_t vaddr = (size_t)(bb * NH + hh) * HSTRIDE + (size_t)(kv0 >> 6) * 4096
                   + (size_t)(((((kvL >> 4) & 3) << 1) + (d >> 5)) * 512)
                   + (size_t)(((((kvL >> 3) & 1) << 5) + (d & 31)) * 8) + (kvL & 7);
      bf16x4 pv = {f2bf(acc[2][mi][ni][0] + bvc), f2bf(acc[2][mi][ni][1] + bvc),
                   f2bf(acc[2][mi][ni][2] + bvc), f2bf(acc[2][mi][ni][3] + bvc)};
      *reinterpret_cast<bf16x4*>(Vw + vaddr) = pv;
    }
}

// ================= output projection (r13 proven: 128x128, 512 blocks = 2/CU) =================
__device__ __forceinline__ void gemm_loop(__bf16* sA, __bf16* sB,
                                          const __bf16* __restrict__ A,
                                          const __bf16* __restrict__ W,
                                          int m0, int n0, f32x4 (&acc)[4][4]) {
  const int t = threadIdx.x;
  const int lane = t & 63, w = t >> 6;
  const int wr = w >> 1, wc = w & 1;
  const int l15 = lane & 15, g = lane >> 4;
  const char* Ac = (const char*)A;
  const char* Wc = (const char*)W;
  const int srow = lane >> 3;
  const int scol = ((lane & 7) ^ srow) * 16;

  int offA[4][2], offB[4][2];
#pragma unroll
  for (int i = 0; i < 4; ++i)
#pragma unroll
    for (int ks = 0; ks < 2; ++ks) {
      int ra = wr * 64 + i * 16 + l15;
      int rb = wc * 64 + i * 16 + l15;
      offA[i][ks] = (ra * 128 + ((ks * 64 + g * 16) ^ ((l15 & 7) << 4))) >> 1;
      offB[i][ks] = (rb * 128 + ((ks * 64 + g * 16) ^ ((l15 & 7) << 4))) >> 1;
    }

#pragma unroll 1
  for (int k0 = 0; k0 < EMB; k0 += 64) {
#pragma unroll
    for (int p = 0; p < 4; ++p) {
      int c = p * 4 + w;
      gll16(Ac + (size_t)(m0 + c * 8 + srow) * (EMB * 2) + k0 * 2 + scol, sA + c * 512);
      gll16(Wc + (size_t)(n0 + c * 8 + srow) * (EMB * 2) + k0 * 2 + scol, sB + c * 512);
    }
    __syncthreads();
    bf16x8 af[4][2], bfr[4][2];
#pragma unroll
    for (int i = 0; i < 4; ++i)
#pragma unroll
      for (int ks = 0; ks < 2; ++ks) {
        af[i][ks]  = *reinterpret_cast<const bf16x8*>(sA + offA[i][ks]);
        bfr[i][ks] = *reinterpret_cast<const bf16x8*>(sB + offB[i][ks]);
      }
#pragma unroll
    for (int ks = 0; ks < 2; ++ks)
#pragma unroll
      for (int mi = 0; mi < 4; ++mi)
#pragma unroll
        for (int ni = 0; ni < 4; ++ni)
          acc[mi][ni] = MFMA16(af[mi][ks], bfr[ni][ks], acc[mi][ni]);
    __syncthreads();
  }
}

__global__ __launch_bounds__(256) void oproj_bf(const __bf16* __restrict__ Abf,
                                                const __bf16* __restrict__ W,
                                                const float* __restrict__ bias,
                                                float* __restrict__ outp) {
  __shared__ __align__(16) __bf16 smem[2][128 * 64];
  int flat = blockIdx.x + 8 * blockIdx.y;
  int logical = (flat & 7) * 64 + (flat >> 3);
  const int m0 = (logical >> 3) * 128, n0 = (logical & 7) * 128;

  f32x4 acc[4][4];
#pragma unroll
  for (int i = 0; i < 4; ++i)
#pragma unroll
    for (int j = 0; j < 4; ++j) acc[i][j] = f32x4{0.f, 0.f, 0.f, 0.f};

  gemm_loop(smem[0], smem[1], Abf, W, m0, n0, acc);

  const int lane = threadIdx.x & 63, w = threadIdx.x >> 6;
  const int wr = w >> 1, wc = w & 1, l15 = lane & 15, g = lane >> 4;
#pragma unroll
  for (int mi = 0; mi < 4; ++mi)
#pragma unroll
    for (int ni = 0; ni < 4; ++ni)
#pragma unroll
      for (int j = 0; j < 4; ++j) {
        int rg = m0 + wr * 64 + mi * 16 + g * 4 + j;
        int cg = n0 + wc * 64 + ni * 16 + l15;
        outp[(size_t)rg * EMB + cg] = acc[mi][ni][j] + bias[cg];
      }
}

// ================= Flash attention: fragment-major K/V, zero-conflict LDS (r21) =================
__global__ __launch_bounds__(512) void flash_kernel(const __bf16* __restrict__ Qb,
                                                    const __bf16* __restrict__ Kb,
                                                    const __bf16* __restrict__ Vb,
                                                    float* __restrict__ attnw,
                                                    __bf16* __restrict__ attnw_bf) {
  __shared__ __align__(16) __bf16 lds[2][16384];  // [buf][ K:8192 | V:8192 ] elements
  const int t = threadIdx.x;
  const int lane = t & 63, w = t >> 6;            // w in [0,8)
  const int l31 = lane & 31, hi = lane >> 5;

  int flat = blockIdx.x + 8 * (blockIdx.y + NH * blockIdx.z);
  int logical = (flat & 7) * 64 + (flat >> 3);
  const int qt = logical & 7, h = (logical >> 3) & 15, b = logical >> 7;

  const size_t hoff = ((size_t)(b * NH + h)) * HSTRIDE;
  const __bf16* Qh = Qb + hoff;                  // [2048][64]
  const char* Kc = (const char*)(Kb + hoff);     // fragment-major, 8KB per 64-row tile
  const char* Vc = (const char*)(Vb + hoff);     // fragment-major, 8KB per 64-kv tile
  const int q0 = qt * 256 + w * 32;              // this wave's 32 q-rows

  bf16x8 qf[4];
#pragma unroll
  for (int ds = 0; ds < 4; ++ds)
    qf[ds] = *reinterpret_cast<const bf16x8*>(Qh + (size_t)(q0 + l31) * DH + ds * 16 + hi * 8);

  // stage a 128-kv tile (K 16KB + V 16KB): pure linear copy, 16 chunks each
  auto stage = [&](int bf, int it) {
#pragma unroll
    for (int j = 0; j < 2; ++j) {
      int chunk = w * 2 + j;
      size_t src = (size_t)it * 16384 + chunk * 1024 + lane * 16;
      gll16(Kc + src, &lds[bf][chunk * 512]);
      gll16(Vc + src, &lds[bf][8192 + chunk * 512]);
    }
  };

  f32x16 o0{}, o1{};
  float lsum = 0.f;                     // per-lane partial row sum (row q = l31)
  const f32x16 kZero{};                 // hoisted zero C operand
  const int lofs = lane * 8;            // element offset of this lane's fragment slot

  stage(0, 0);
  __syncthreads();

#pragma unroll 1
  for (int it = 0; it < NSEQ / 128; ++it) {
    const int cur = it & 1;
    if (it + 1 < NSEQ / 128) stage(cur ^ 1, it + 1);

#pragma unroll
    for (int sub = 0; sub < 2; ++sub) {
      const __bf16* Kl = lds[cur] + sub * 4096;
      const __bf16* Vl = lds[cur] + 8192 + sub * 4096;

      bf16x8 kf[2][4];
#pragma unroll
      for (int kt32 = 0; kt32 < 2; ++kt32)
#pragma unroll
        for (int ds = 0; ds < 4; ++ds)
          kf[kt32][ds] = *reinterpret_cast<const bf16x8*>(Kl + (kt32 * 4 + ds) * 512 + lofs);

      f32x16 s0, s1;
      __builtin_amdgcn_s_setprio(1);
      s0 = MFMA32(kf[0][0], qf[0], kZero);
      s1 = MFMA32(kf[1][0], qf[0], kZero);
#pragma unroll
      for (int ds = 1; ds < 4; ++ds) s0 = MFMA32(kf[0][ds], qf[ds], s0);
#pragma unroll
      for (int ds = 1; ds < 4; ++ds) s1 = MFMA32(kf[1][ds], qf[ds], s1);
      __builtin_amdgcn_s_setprio(0);

      bf16x8 vf[4][2];
#pragma unroll
      for (int c = 0; c < 4; ++c)
#pragma unroll
        for (int db = 0; db < 2; ++db)
          vf[c][db] = *reinterpret_cast<const bf16x8*>(Vl + (c * 2 + db) * 512 + lofs);

      // softmax: p = exp2(S) via raw v_exp_f32 (no IEEE denormal fixup)
#pragma unroll
      for (int r = 0; r < 16; ++r) s0[r] = __builtin_amdgcn_exp2f(s0[r]);
#pragma unroll
      for (int r = 0; r < 16; ++r) s1[r] = __builtin_amdgcn_exp2f(s1[r]);

      // denominator on the VALU (slack pipe): tree-sum 32 values
      {
        float t0 = ((s0[0] + s0[1]) + (s0[2] + s0[3])) + ((s0[4] + s0[5]) + (s0[6] + s0[7]));
        float t1 = ((s0[8] + s0[9]) + (s0[10] + s0[11])) + ((s0[12] + s0[13]) + (s0[14] + s0[15]));
        float t2 = ((s1[0] + s1[1]) + (s1[2] + s1[3])) + ((s1[4] + s1[5]) + (s1[6] + s1[7]));
        float t3 = ((s1[8] + s1[9]) + (s1[10] + s1[11])) + ((s1[12] + s1[13]) + (s1[14] + s1[15]));
        lsum += (t0 + t1) + (t2 + t3);
      }

      u32 pk0[8], pk1[8];
#pragma unroll
      for (int j = 0; j < 8; ++j) pk0[j] = pkbf(s0[2 * j], s0[2 * j + 1]);
#pragma unroll
      for (int j = 0; j < 8; ++j) pk1[j] = pkbf(s1[2 * j], s1[2 * j + 1]);

      auto pv_step = [&](u32& a0, u32& a1, u32& a2, u32& a3, int c) {
        asm("v_permlane32_swap_b32 %0, %1" : "+v"(a0), "+v"(a2));
        asm("v_permlane32_swap_b32 %0, %1" : "+v"(a1), "+v"(a3));
        u32x4 wv = {a0, a1, a2, a3};
        bf16x8 pa = __builtin_bit_cast(bf16x8, wv);
        o0 = MFMA32(pa, vf[c][0], o0);
        o1 = MFMA32(pa, vf[c][1], o1);
      };
      __builtin_amdgcn_s_setprio(1);
      pv_step(pk0[0], pk0[1], pk0[2], pk0[3], 0);
      pv_step(pk0[4], pk0[5], pk0[6], pk0[7], 1);
      pv_step(pk1[0], pk1[1], pk1[2], pk1[3], 2);
      pv_step(pk1[4], pk1[5], pk1[6], pk1[7], 3);
      __builtin_amdgcn_s_setprio(0);
    }

    __syncthreads();   // drains staging vmcnt + lgkm; safe buffer flip
  }

  // row total: lane covers half the k's of row q=l31; partner has the rest
  lsum += __shfl_xor(lsum, 32);
  float inv = 1.0f / lsum;

#pragma unroll
  for (int r = 0; r < 16; ++r) {
    int qq = (r & 3) + 8 * (r >> 2) + 4 * hi;
    float invq = __shfl(inv, qq);        // lane qq holds row qq's inv
    int row = q0 + qq;
    float v0 = o0[r] * invq, v1 = o1[r] * invq;
    float* base = attnw + ((size_t)(b * NSEQ + row)) * EMB + h * DH;
    base[l31]      = v0;
    base[32 + l31] = v1;
    __bf16* bb2 = attnw_bf + ((size_t)(b * NSEQ + row)) * EMB + h * DH;
    bb2[l31]      = f2bf(v0);
    bb2[32 + l31] = f2bf(v1);
  }
}

extern "C" void kernel_launch(void* const* d_in, const int* in_sizes, int n_in,
                              void* d_out, int out_size, void* d_ws, size_t ws_size,
                              hipStream_t stream) {
  const float* q  = (const float*)d_in[0];
  const float* Wq = (const float*)d_in[1];
  const float* bq = (const float*)d_in[2];
  const float* Wk = (const float*)d_in[3];
  const float* bk = (const float*)d_in[4];
  const float* Wv = (const float*)d_in[5];
  const float* bv = (const float*)d_in[6];
  const float* Wo = (const float*)d_in[7];
  const float* bo = (const float*)d_in[8];

  float* outp  = (float*)d_out;
  float* attnw = outp + MAT;            // second tuple element

  // ws = Q | K | V | Xbf(->attnw_bf) | Wbf[4]   (bf16; ~75.5 MB, fits: r7)
  __bf16* Qw   = (__bf16*)d_ws;
  __bf16* Kw   = Qw + MAT;              // fragment-major per head
  __bf16* Vw   = Qw + 2 * MAT;          // fragment-major per head
  __bf16* Xbf  = Qw + 3 * MAT;          // aliased as attnw_bf after qkv
  __bf16* Wbf  = Qw + 4 * MAT;

  const int xblocks = (int)(MAT / 4 / 256);
  const int wblocks = (int)(4 * WSZ / 4 / 256);
  cvt_all<<<xblocks + wblocks, 256, 0, stream>>>(q, Wq, Wk, Wv, Wo, Xbf, Wbf);

  qkv3<<<dim3(16, 64), 256, 0, stream>>>(Xbf, Wbf, bq, bk, bv, Qw, Kw, Vw);

  flash_kernel<<<dim3(8, NH, NB), 512, 0, stream>>>(Qw, Kw, Vw, attnw, Xbf);

  oproj_bf<<<dim3(8, 64), 256, 0, stream>>>(Xbf, Wbf + 3 * WSZ, bo, outp);
}

// Round 24
// 182.490 us; speedup vs baseline: 1.1191x; 1.0172x over previous
//
#include <hip/hip_runtime.h>

typedef float  f32x4  __attribute__((ext_vector_type(4)));
typedef float  f32x16 __attribute__((ext_vector_type(16)));
typedef __bf16 bf16x2 __attribute__((ext_vector_type(2)));
typedef __bf16 bf16x4 __attribute__((ext_vector_type(4)));
typedef __bf16 bf16x8 __attribute__((ext_vector_type(8)));
typedef unsigned int u32;
typedef u32 u32x4 __attribute__((ext_vector_type(4)));

#define MFMA16(a, b, c) __builtin_amdgcn_mfma_f32_16x16x32_bf16((a), (b), (c), 0, 0, 0)
#define MFMA32(a, b, c) __builtin_amdgcn_mfma_f32_32x32x16_bf16((a), (b), (c), 0, 0, 0)

constexpr int EMB  = 1024;
constexpr int NSEQ = 2048;
constexpr int NB   = 4;
constexpr int NH   = 16;
constexpr int DH   = 64;
constexpr size_t HSTRIDE = (size_t)NSEQ * DH;        // elements per head (Q/K/V)
constexpr size_t MAT     = (size_t)NB * NSEQ * EMB;  // 8388608
constexpr size_t WSZ     = (size_t)EMB * EMB;        // 1048576
constexpr float  QSCALE  = 0.18033688011112042f;     // 0.125 * log2(e)

__device__ __forceinline__ __bf16 f2bf(float f) { return (__bf16)f; }

__device__ __forceinline__ u32 pkbf(float a, float b) {
  bf16x2 t = {(__bf16)a, (__bf16)b};
  return __builtin_bit_cast(u32, t);
}

// XOR swizzle (involution) for 128B-row tiles (GEMM staging only).
__device__ __forceinline__ int swz(int a) { return a ^ (((a >> 7) & 7) << 4); }

// async global->LDS, 16B per lane; LDS dest = wave-uniform base + lane*16.
__device__ __forceinline__ void gll16(const void* g, void* l) {
  __builtin_amdgcn_global_load_lds((const __attribute__((address_space(1))) unsigned*)g,
                                   (__attribute__((address_space(3))) unsigned*)l, 16, 0, 0);
}

// ================= conversion pre-pass (single launch) =================
__global__ __launch_bounds__(256) void cvt_all(const float* __restrict__ x,
                                               const float* __restrict__ w0,
                                               const float* __restrict__ w1,
                                               const float* __restrict__ w2,
                                               const float* __restrict__ w3,
                                               __bf16* __restrict__ Xbf,
                                               __bf16* __restrict__ Wbf) {
  const int xblocks = (int)(MAT / 4 / 256);
  const int wslice  = (int)(WSZ / 4 / 256);
  const float* src;
  __bf16* dst;
  size_t idx;
  if (blockIdx.x < (unsigned)xblocks) {
    src = x; dst = Xbf;
    idx = (size_t)blockIdx.x * 256 + threadIdx.x;
  } else {
    int j = blockIdx.x - xblocks;
    int z = j / wslice, r = j % wslice;
    const float* srcs[4] = {w0, w1, w2, w3};
    src = srcs[z];
    dst = Wbf + (size_t)z * WSZ;
    idx = (size_t)r * 256 + threadIdx.x;
  }
  f32x4 v = *reinterpret_cast<const f32x4*>(src + idx * 4);
  bf16x4 o = {f2bf(v[0]), f2bf(v[1]), f2bf(v[2]), f2bf(v[3])};
  *reinterpret_cast<bf16x4*>(dst + idx * 4) = o;
}

// ================= fused 3-output QKV GEMM, 128x64 tile (r23 proven) =================
// Q -> [b][h][n][d] (prescaled). K,V -> FRAGMENT-MAJOR per (b,h):
//  K elem (row,d): tile=row>>6, f=((row>>5)&1)*4+(d>>4),
//                  lane=((d>>3)&1)*32+(row&31), i=d&7
//  V elem (kv,d):  tile=kv>>6,  f=((kv>>4)&3)*2+(d>>5),
//                  lane=((kv>>3)&1)*32+(d&31),  i=kv&7
__global__ __launch_bounds__(256) void qkv3(const __bf16* __restrict__ Xbf,
                                            const __bf16* __restrict__ Wbf,
                                            const float* __restrict__ bq,
                                            const float* __restrict__ bk,
                                            const float* __restrict__ bv,
                                            __bf16* __restrict__ Qw,
                                            __bf16* __restrict__ Kw,
                                            __bf16* __restrict__ Vw) {
  __shared__ __align__(16) __bf16 sA[128 * 64];        // 16KB
  __shared__ __align__(16) __bf16 sW[3][64 * 64];      // 3 x 8KB
  const int t = threadIdx.x;
  const int lane = t & 63, w = t >> 6;
  const int l15 = lane & 15, g = lane >> 4;

  // bijective XCD remap over 1024 blocks
  int flat = blockIdx.x + 16 * blockIdx.y;
  int logical = (flat & 7) * 128 + (flat >> 3);
  const int m0 = (logical >> 4) * 128, n0 = (logical & 15) * 64;

  const char* Ac  = (const char*)Xbf;
  const char* Wc[3] = {(const char*)(Wbf + 0 * WSZ),
                       (const char*)(Wbf + 1 * WSZ),
                       (const char*)(Wbf + 2 * WSZ)};

  const int srow = lane >> 3;                          // 8 rows / chunk
  const int scol = ((lane & 7) ^ srow) * 16;           // pre-swizzled source col byte

  int offA[2][2], offB[4][2];
#pragma unroll
  for (int i = 0; i < 2; ++i)
#pragma unroll
    for (int ks = 0; ks < 2; ++ks) {
      int ra = w * 32 + i * 16 + l15;
      offA[i][ks] = (ra * 128 + ((ks * 64 + g * 16) ^ ((l15 & 7) << 4))) >> 1;
    }
#pragma unroll
  for (int i = 0; i < 4; ++i)
#pragma unroll
    for (int ks = 0; ks < 2; ++ks) {
      int rb = i * 16 + l15;
      offB[i][ks] = (rb * 128 + ((ks * 64 + g * 16) ^ ((l15 & 7) << 4))) >> 1;
    }

  f32x4 acc[3][2][4];
#pragma unroll
  for (int m = 0; m < 3; ++m)
#pragma unroll
    for (int i = 0; i < 2; ++i)
#pragma unroll
      for (int j = 0; j < 4; ++j) acc[m][i][j] = f32x4{0.f, 0.f, 0.f, 0.f};

#pragma unroll 1
  for (int k0 = 0; k0 < EMB; k0 += 64) {
#pragma unroll
    for (int p = 0; p < 4; ++p) {
      int c = p * 4 + w;
      gll16(Ac + (size_t)(m0 + c * 8 + srow) * (EMB * 2) + k0 * 2 + scol, sA + c * 512);
    }
#pragma unroll
    for (int p = 0; p < 2; ++p) {
      int c = p * 4 + w;
      size_t rowB = (size_t)(n0 + c * 8 + srow) * (EMB * 2) + k0 * 2 + scol;
#pragma unroll
      for (int mat = 0; mat < 3; ++mat)
        gll16(Wc[mat] + rowB, &sW[mat][c * 512]);
    }
    __syncthreads();   // drains vmcnt: staged tiles visible
#pragma unroll
    for (int ks = 0; ks < 2; ++ks) {
      bf16x8 af[2];
#pragma unroll
      for (int i = 0; i < 2; ++i)
        af[i] = *reinterpret_cast<const bf16x8*>(&sA[offA[i][ks]]);
#pragma unroll
      for (int mat = 0; mat < 3; ++mat) {
        bf16x8 bf[4];
#pragma unroll
        for (int i = 0; i < 4; ++i)
          bf[i] = *reinterpret_cast<const bf16x8*>(&sW[mat][offB[i][ks]]);
#pragma unroll
        for (int mi = 0; mi < 2; ++mi)
#pragma unroll
          for (int ni = 0; ni < 4; ++ni)
            acc[mat][mi][ni] = MFMA16(af[mi], bf[ni], acc[mat][mi][ni]);
      }
    }
    __syncthreads();   // tiles consumed; safe to restage
  }

  // ---- epilogue ----  (C/D: row=(lane>>4)*4+reg, col=lane&15)
  const int hh = n0 >> 6;                              // one head per block
#pragma unroll
  for (int mi = 0; mi < 2; ++mi)
#pragma unroll
    for (int ni = 0; ni < 4; ++ni) {
      int cg = n0 + ni * 16 + l15;
      int d = cg & (DH - 1);
#pragma unroll
      for (int j = 0; j < 4; ++j) {
        int rg = m0 + w * 32 + mi * 16 + g * 4 + j;
        int bb = rg >> 11, r = rg & (NSEQ - 1);
        size_t hb = (size_t)(bb * NH + hh);
        // Q: [b][h][n][d]
        Qw[(hb * NSEQ + r) * DH + d] = f2bf((acc[0][mi][ni][j] + bq[cg]) * QSCALE);
        // K: fragment-major
        size_t kidx = hb * HSTRIDE + (size_t)(r >> 6) * 4096
                    + (size_t)(((((r >> 5) & 1) << 2) + (d >> 4)) * 512)
                    + (size_t)(((((d >> 3) & 1) << 5) + (r & 31)) * 8) + (d & 7);
        Kw[kidx] = f2bf(acc[1][mi][ni][j] + bk[cg]);
      }
      // V: fragment-major; 4 consecutive kv (=i0..i0+3) -> one 8B store
      float bvc = bv[cg];
      int rg0 = m0 + w * 32 + mi * 16 + g * 4;
      int bb = rg0 >> 11, kv0 = rg0 & (NSEQ - 1);
      int kvL = kv0 & 63;
      size_t vaddr = (size_t)(bb * NH + hh) * HSTRIDE + (size_t)(kv0 >> 6) * 4096
                   + (size_t)(((((kvL >> 4) & 3) << 1) + (d >> 5)) * 512)
                   + (size_t)(((((kvL >> 3) & 1) << 5) + (d & 31)) * 8) + (kvL & 7);
      bf16x4 pv = {f2bf(acc[2][mi][ni][0] + bvc), f2bf(acc[2][mi][ni][1] + bvc),
                   f2bf(acc[2][mi][ni][2] + bvc), f2bf(acc[2][mi][ni][3] + bvc)};
      *reinterpret_cast<bf16x4*>(Vw + vaddr) = pv;
    }
}

// ================= output projection: 128x128, low-VGPR inner loop, 4 blocks/CU =================
// Same math/schedule as r23's oproj, but fragments held live are af[4]+one bfr
// (20 VGPR vs 64) and __launch_bounds__(256,4) pins VGPR<=128 -> 4 waves/SIMD
// -> 4 desynced resident blocks/CU (vs ~2), covering the barrier drains.
__global__ __launch_bounds__(256, 4) void oproj_bf(const __bf16* __restrict__ Abf,
                                                   const __bf16* __restrict__ W,
                                                   const float* __restrict__ bias,
                                                   float* __restrict__ outp) {
  __shared__ __align__(16) __bf16 smem[2][128 * 64];
  const int t = threadIdx.x;
  const int lane = t & 63, w = t >> 6;
  const int wr = w >> 1, wc = w & 1;
  const int l15 = lane & 15, g = lane >> 4;
  int flat = blockIdx.x + 8 * blockIdx.y;
  int logical = (flat & 7) * 64 + (flat >> 3);
  const int m0 = (logical >> 3) * 128, n0 = (logical & 7) * 128;

  const char* Ac = (const char*)Abf;
  const char* Wc = (const char*)W;
  const int srow = lane >> 3;
  const int scol = ((lane & 7) ^ srow) * 16;

  int offA[4][2], offB[4][2];
#pragma unroll
  for (int i = 0; i < 4; ++i)
#pragma unroll
    for (int ks = 0; ks < 2; ++ks) {
      int ra = wr * 64 + i * 16 + l15;
      int rb = wc * 64 + i * 16 + l15;
      offA[i][ks] = (ra * 128 + ((ks * 64 + g * 16) ^ ((l15 & 7) << 4))) >> 1;
      offB[i][ks] = (rb * 128 + ((ks * 64 + g * 16) ^ ((l15 & 7) << 4))) >> 1;
    }

  f32x4 acc[4][4];
#pragma unroll
  for (int i = 0; i < 4; ++i)
#pragma unroll
    for (int j = 0; j < 4; ++j) acc[i][j] = f32x4{0.f, 0.f, 0.f, 0.f};

#pragma unroll 1
  for (int k0 = 0; k0 < EMB; k0 += 64) {
#pragma unroll
    for (int p = 0; p < 4; ++p) {
      int c = p * 4 + w;
      gll16(Ac + (size_t)(m0 + c * 8 + srow) * (EMB * 2) + k0 * 2 + scol, &smem[0][c * 512]);
      gll16(Wc + (size_t)(n0 + c * 8 + srow) * (EMB * 2) + k0 * 2 + scol, &smem[1][c * 512]);
    }
    __syncthreads();
#pragma unroll
    for (int ks = 0; ks < 2; ++ks) {
      bf16x8 af[4];
#pragma unroll
      for (int i = 0; i < 4; ++i)
        af[i] = *reinterpret_cast<const bf16x8*>(&smem[0][offA[i][ks]]);
#pragma unroll
      for (int ni = 0; ni < 4; ++ni) {
        bf16x8 bfr = *reinterpret_cast<const bf16x8*>(&smem[1][offB[ni][ks]]);
#pragma unroll
        for (int mi = 0; mi < 4; ++mi)
          acc[mi][ni] = MFMA16(af[mi], bfr, acc[mi][ni]);
      }
    }
    __syncthreads();
  }

#pragma unroll
  for (int mi = 0; mi < 4; ++mi)
#pragma unroll
    for (int ni = 0; ni < 4; ++ni) {
      int cg = n0 + wc * 64 + ni * 16 + l15;
      float bc = bias[cg];
#pragma unroll
      for (int j = 0; j < 4; ++j) {
        int rg = m0 + wr * 64 + mi * 16 + g * 4 + j;
        outp[(size_t)rg * EMB + cg] = acc[mi][ni][j] + bc;
      }
    }
}

// ================= Flash attention: fragment-major K/V, zero-conflict LDS (r23) =================
__global__ __launch_bounds__(512) void flash_kernel(const __bf16* __restrict__ Qb,
                                                    const __bf16* __restrict__ Kb,
                                                    const __bf16* __restrict__ Vb,
                                                    float* __restrict__ attnw,
                                                    __bf16* __restrict__ attnw_bf) {
  __shared__ __align__(16) __bf16 lds[2][16384];  // [buf][ K:8192 | V:8192 ] elements
  const int t = threadIdx.x;
  const int lane = t & 63, w = t >> 6;            // w in [0,8)
  const int l31 = lane & 31, hi = lane >> 5;

  int flat = blockIdx.x + 8 * (blockIdx.y + NH * blockIdx.z);
  int logical = (flat & 7) * 64 + (flat >> 3);
  const int qt = logical & 7, h = (logical >> 3) & 15, b = logical >> 7;

  const size_t hoff = ((size_t)(b * NH + h)) * HSTRIDE;
  const __bf16* Qh = Qb + hoff;                  // [2048][64]
  const char* Kc = (const char*)(Kb + hoff);     // fragment-major, 8KB per 64-row tile
  const char* Vc = (const char*)(Vb + hoff);     // fragment-major, 8KB per 64-kv tile
  const int q0 = qt * 256 + w * 32;              // this wave's 32 q-rows

  bf16x8 qf[4];
#pragma unroll
  for (int ds = 0; ds < 4; ++ds)
    qf[ds] = *reinterpret_cast<const bf16x8*>(Qh + (size_t)(q0 + l31) * DH + ds * 16 + hi * 8);

  // stage a 128-kv tile (K 16KB + V 16KB): pure linear copy, 16 chunks each
  auto stage = [&](int bf, int it) {
#pragma unroll
    for (int j = 0; j < 2; ++j) {
      int chunk = w * 2 + j;
      size_t src = (size_t)it * 16384 + chunk * 1024 + lane * 16;
      gll16(Kc + src, &lds[bf][chunk * 512]);
      gll16(Vc + src, &lds[bf][8192 + chunk * 512]);
    }
  };

  f32x16 o0{}, o1{};
  float lsum = 0.f;                     // per-lane partial row sum (row q = l31)
  const f32x16 kZero{};                 // hoisted zero C operand
  const int lofs = lane * 8;            // element offset of this lane's fragment slot

  stage(0, 0);
  __syncthreads();

#pragma unroll 1
  for (int it = 0; it < NSEQ / 128; ++it) {
    const int cur = it & 1;
    if (it + 1 < NSEQ / 128) stage(cur ^ 1, it + 1);

#pragma unroll
    for (int sub = 0; sub < 2; ++sub) {
      const __bf16* Kl = lds[cur] + sub * 4096;
      const __bf16* Vl = lds[cur] + 8192 + sub * 4096;

      bf16x8 kf[2][4];
#pragma unroll
      for (int kt32 = 0; kt32 < 2; ++kt32)
#pragma unroll
        for (int ds = 0; ds < 4; ++ds)
          kf[kt32][ds] = *reinterpret_cast<const bf16x8*>(Kl + (kt32 * 4 + ds) * 512 + lofs);

      f32x16 s0, s1;
      __builtin_amdgcn_s_setprio(1);
      s0 = MFMA32(kf[0][0], qf[0], kZero);
      s1 = MFMA32(kf[1][0], qf[0], kZero);
#pragma unroll
      for (int ds = 1; ds < 4; ++ds) s0 = MFMA32(kf[0][ds], qf[ds], s0);
#pragma unroll
      for (int ds = 1; ds < 4; ++ds) s1 = MFMA32(kf[1][ds], qf[ds], s1);
      __builtin_amdgcn_s_setprio(0);

      bf16x8 vf[4][2];
#pragma unroll
      for (int c = 0; c < 4; ++c)
#pragma unroll
        for (int db = 0; db < 2; ++db)
          vf[c][db] = *reinterpret_cast<const bf16x8*>(Vl + (c * 2 + db) * 512 + lofs);

      // softmax: p = exp2(S) via raw v_exp_f32 (no IEEE denormal fixup)
#pragma unroll
      for (int r = 0; r < 16; ++r) s0[r] = __builtin_amdgcn_exp2f(s0[r]);
#pragma unroll
      for (int r = 0; r < 16; ++r) s1[r] = __builtin_amdgcn_exp2f(s1[r]);

      // denominator on the VALU (slack pipe): tree-sum 32 values
      {
        float t0 = ((s0[0] + s0[1]) + (s0[2] + s0[3])) + ((s0[4] + s0[5]) + (s0[6] + s0[7]));
        float t1 = ((s0[8] + s0[9]) + (s0[10] + s0[11])) + ((s0[12] + s0[13]) + (s0[14] + s0[15]));
        float t2 = ((s1[0] + s1[1]) + (s1[2] + s1[3])) + ((s1[4] + s1[5]) + (s1[6] + s1[7]));
        float t3 = ((s1[8] + s1[9]) + (s1[10] + s1[11])) + ((s1[12] + s1[13]) + (s1[14] + s1[15]));
        lsum += (t0 + t1) + (t2 + t3);
      }

      u32 pk0[8], pk1[8];
#pragma unroll
      for (int j = 0; j < 8; ++j) pk0[j] = pkbf(s0[2 * j], s0[2 * j + 1]);
#pragma unroll
      for (int j = 0; j < 8; ++j) pk1[j] = pkbf(s1[2 * j], s1[2 * j + 1]);

      auto pv_step = [&](u32& a0, u32& a1, u32& a2, u32& a3, int c) {
        asm("v_permlane32_swap_b32 %0, %1" : "+v"(a0), "+v"(a2));
        asm("v_permlane32_swap_b32 %0, %1" : "+v"(a1), "+v"(a3));
        u32x4 wv = {a0, a1, a2, a3};
        bf16x8 pa = __builtin_bit_cast(bf16x8, wv);
        o0 = MFMA32(pa, vf[c][0], o0);
        o1 = MFMA32(pa, vf[c][1], o1);
      };
      __builtin_amdgcn_s_setprio(1);
      pv_step(pk0[0], pk0[1], pk0[2], pk0[3], 0);
      pv_step(pk0[4], pk0[5], pk0[6], pk0[7], 1);
      pv_step(pk1[0], pk1[1], pk1[2], pk1[3], 2);
      pv_step(pk1[4], pk1[5], pk1[6], pk1[7], 3);
      __builtin_amdgcn_s_setprio(0);
    }

    __syncthreads();   // drains staging vmcnt + lgkm; safe buffer flip
  }

  // row total: lane covers half the k's of row q=l31; partner has the rest
  lsum += __shfl_xor(lsum, 32);
  float inv = 1.0f / lsum;

#pragma unroll
  for (int r = 0; r < 16; ++r) {
    int qq = (r & 3) + 8 * (r >> 2) + 4 * hi;
    float invq = __shfl(inv, qq);        // lane qq holds row qq's inv
    int row = q0 + qq;
    float v0 = o0[r] * invq, v1 = o1[r] * invq;
    float* base = attnw + ((size_t)(b * NSEQ + row)) * EMB + h * DH;
    base[l31]      = v0;
    base[32 + l31] = v1;
    __bf16* bb2 = attnw_bf + ((size_t)(b * NSEQ + row)) * EMB + h * DH;
    bb2[l31]      = f2bf(v0);
    bb2[32 + l31] = f2bf(v1);
  }
}

extern "C" void kernel_launch(void* const* d_in, const int* in_sizes, int n_in,
                              void* d_out, int out_size, void* d_ws, size_t ws_size,
                              hipStream_t stream) {
  const float* q  = (const float*)d_in[0];
  const float* Wq = (const float*)d_in[1];
  const float* bq = (const float*)d_in[2];
  const float* Wk = (const float*)d_in[3];
  const float* bk = (const float*)d_in[4];
  const float* Wv = (const float*)d_in[5];
  const float* bv = (const float*)d_in[6];
  const float* Wo = (const float*)d_in[7];
  const float* bo = (const float*)d_in[8];

  float* outp  = (float*)d_out;
  float* attnw = outp + MAT;            // second tuple element

  // ws = Q | K | V | Xbf(->attnw_bf) | Wbf[4]   (bf16; ~75.5 MB, fits: r7)
  __bf16* Qw   = (__bf16*)d_ws;
  __bf16* Kw   = Qw + MAT;              // fragment-major per head
  __bf16* Vw   = Qw + 2 * MAT;          // fragment-major per head
  __bf16* Xbf  = Qw + 3 * MAT;          // aliased as attnw_bf after qkv
  __bf16* Wbf  = Qw + 4 * MAT;

  const int xblocks = (int)(MAT / 4 / 256);
  const int wblocks = (int)(4 * WSZ / 4 / 256);
  cvt_all<<<xblocks + wblocks, 256, 0, stream>>>(q, Wq, Wk, Wv, Wo, Xbf, Wbf);

  qkv3<<<dim3(16, 64), 256, 0, stream>>>(Xbf, Wbf, bq, bk, bv, Qw, Kw, Vw);

  flash_kernel<<<dim3(8, NH, NB), 512, 0, stream>>>(Qw, Kw, Vw, attnw, Xbf);

  oproj_bf<<<dim3(8, 64), 256, 0, stream>>>(Xbf, Wbf + 3 * WSZ, bo, outp);
}